// Round 6
// baseline (186.681 us; speedup 1.0000x reference)
//
#include <hip/hip_runtime.h>
#include <stdint.h>

typedef uint64_t u64;
typedef uint32_t u32;

#define NB    8
#define NQ    4096
#define NKEY  4096
#define CV    64
#define KSEL  16
#define NWAVE 4              /* waves per block; 1 query per wave */
#define BLK   (NWAVE * 64)   /* 256 threads */
#define CMAX  64             /* candidate slots per wave */
#define PADU  (~(u64)0)      /* > any transformed candidate */

__device__ __forceinline__ u64 shflxor_u64(u64 v, int m) {
    const u32 lo = __shfl_xor((int)(u32)v, m);
    const u32 hi = __shfl_xor((int)(u32)(v >> 32), m);
    return (((u64)hi) << 32) | lo;
}
__device__ __forceinline__ int mbcnt64(u64 m) {
    return (int)__builtin_amdgcn_mbcnt_hi((u32)(m >> 32),
               __builtin_amdgcn_mbcnt_lo((u32)m, 0));
}
/* monotone float -> u32 key (handles negatives) */
__device__ __forceinline__ u32 fkey(float f) {
    const u32 b = __float_as_uint(f);
    return b ^ (0x80000000u | (u32)((int32_t)b >> 31));
}

/* full 64-lane bitonic sort, ascending (for the threshold order-statistic) */
__device__ __forceinline__ float lanesort64_f32(float v, int lane) {
#pragma unroll
    for (int k = 2; k <= 64; k <<= 1) {
#pragma unroll
        for (int j = k >> 1; j > 0; j >>= 1) {
            const float p = __shfl_xor(v, j);
            const bool up    = ((lane & k) == 0);
            const bool lower = ((lane & j) == 0);
            v = (lower == up) ? fminf(v, p) : fmaxf(v, p);
        }
    }
    return v;
}

/* EXACT smallest-16 SET of 64 lane values -> lanes 0..15 (bitonic order).
   sort16/group (alt dirs) -> half-clean xor16 -> merge16 asc/desc -> xor32. */
__device__ __forceinline__ u64 top16of64(u64 v, int lane) {
#pragma unroll
    for (int k = 2; k <= 16; k <<= 1) {
#pragma unroll
        for (int j = k >> 1; j > 0; j >>= 1) {
            const u64 p = shflxor_u64(v, j);
            const bool up    = ((lane & k) == 0);
            const bool lower = ((lane & j) == 0);
            const u64 mn = v < p ? v : p, mx = v < p ? p : v;
            v = (lower == up) ? mn : mx;
        }
    }
    {   const u64 p = shflxor_u64(v, 16);
        const u64 mn = v < p ? v : p, mx = v < p ? p : v;
        v = ((lane & 16) == 0) ? mn : mx; }
#pragma unroll
    for (int j = 8; j > 0; j >>= 1) {
        const u64 p = shflxor_u64(v, j);
        const bool lower = ((lane & j) == 0);
        const bool dasc  = ((lane & 32) == 0);
        const u64 mn = v < p ? v : p, mx = v < p ? p : v;
        v = (lower == dasc) ? mn : mx;
    }
    {   const u64 p = shflxor_u64(v, 32);
        const u64 mn = v < p ? v : p, mx = v < p ? p : v;
        v = ((lane & 32) == 0) ? mn : mx; }
    return v;
}

/* setup: expand K -> (kx,ky,k2,0) in ws; block 0 also reduces the 9 affine sums */
__global__ void setup_kernel(const float* __restrict__ kg,
                             const float* __restrict__ qw, const float* __restrict__ qb,
                             const float* __restrict__ kw, const float* __restrict__ kb,
                             float* __restrict__ w9, float4* __restrict__ kq4, int dok2)
{
    const int gid = blockIdx.x * 256 + threadIdx.x;
    if (dok2 && gid < NB * NKEY) {
        const float2 kc = ((const float2*)kg)[gid];
        kq4[gid] = make_float4(kc.x, kc.y, fmaf(kc.x, kc.x, kc.y * kc.y), 0.f);
    }
    if (blockIdx.x == 0 && threadIdx.x < 64) {
        const int h = threadIdx.x;
        const float2 a = ((const float2*)qw)[h];
        const float2 c = ((const float2*)kw)[h];
        const float qbh = qb[h], kbh = kb[h];
        float s[9] = { a.x * c.x, a.y * c.x, qbh * c.x,
                       a.x * c.y, a.y * c.y, qbh * c.y,
                       a.x * kbh, a.y * kbh, qbh * kbh };
#pragma unroll
        for (int i = 0; i < 9; ++i)
#pragma unroll
            for (int off = 32; off; off >>= 1) s[i] += __shfl_xor(s[i], off);
        if (h == 0) {
#pragma unroll
            for (int i = 0; i < 9; ++i) w9[i] = s[i];
        }
    }
}

/* MODE 0: cmp = k2 - 2 q.k from precomputed float4 (ws). MODE 1: direct d2. */
template<int MODE>
__global__ __launch_bounds__(BLK, 8) void bev_main(
    const float* __restrict__ qg, const float* __restrict__ kg,
    const float* __restrict__ vg, const float* __restrict__ w9,
    const float4* __restrict__ kq4, float* __restrict__ outg)
{
    __shared__ u64 cand[NWAVE][CMAX];         /* 2 KB; per-wave private */

    const int tid  = threadIdx.x;
    const int wv   = tid >> 6;
    const int lane = tid & 63;
    const int b    = blockIdx.x >> 10;                 /* 1024 blocks per batch */
    const int qi   = ((blockIdx.x & 1023) << 2) + wv;  /* 1 query per wave */

    const float2* kp = (const float2*)(kg + (size_t)b * NKEY * 2);
    const float2  qc = ((const float2*)qg)[(size_t)b * NQ + qi];
    const float qx = qc.x, qy = qc.y;
    const float m2qx = -2.f * qx, m2qy = -2.f * qy;
    const float4* kb4 = kq4 + (size_t)b * NKEY;        /* MODE 0 layout */
    const float4* kp4 = (const float4*)kp;             /* MODE 1: 2 keys / 16B */

    /* ---- pass 1: per-lane min of metric over its 64 keys (4 accum ILP) ---- */
    float mn0 = __builtin_inff(), mn1 = mn0, mn2 = mn0, mn3 = mn0;
    if (MODE == 0) {
#pragma unroll
        for (int c = 0; c < 64; c += 4) {
            const float4 a0 = kb4[(c + 0) * 64 + lane];
            const float4 a1 = kb4[(c + 1) * 64 + lane];
            const float4 a2 = kb4[(c + 2) * 64 + lane];
            const float4 a3 = kb4[(c + 3) * 64 + lane];
            mn0 = fminf(mn0, fmaf(a0.x, m2qx, fmaf(a0.y, m2qy, a0.z)));
            mn1 = fminf(mn1, fmaf(a1.x, m2qx, fmaf(a1.y, m2qy, a1.z)));
            mn2 = fminf(mn2, fmaf(a2.x, m2qx, fmaf(a2.y, m2qy, a2.z)));
            mn3 = fminf(mn3, fmaf(a3.x, m2qx, fmaf(a3.y, m2qy, a3.z)));
        }
    } else {
#pragma unroll
        for (int c = 0; c < 32; c += 2) {
            const float4 k0 = kp4[(c + 0) * 64 + lane];
            const float4 k1 = kp4[(c + 1) * 64 + lane];
            { const float dx = qx - k0.x, dy = qy - k0.y; mn0 = fminf(mn0, fmaf(dx, dx, dy * dy)); }
            { const float dx = qx - k0.z, dy = qy - k0.w; mn1 = fminf(mn1, fmaf(dx, dx, dy * dy)); }
            { const float dx = qx - k1.x, dy = qy - k1.y; mn2 = fminf(mn2, fmaf(dx, dx, dy * dy)); }
            { const float dx = qx - k1.z, dy = qy - k1.w; mn3 = fminf(mn3, fmaf(dx, dx, dy * dy)); }
        }
    }
    const float mn  = fminf(fminf(mn0, mn1), fminf(mn2, mn3));
    /* threshold = 16th-smallest of 64 lane-minima: >=16 keys <= thr, E[cnt]~18 */
    const float thr = __shfl(lanesort64_f32(mn, lane), 15);

    /* ---- pass 2: recompute metric, ballot-append all <= thr ---- */
    int cnt = 0;
    if (MODE == 0) {
#pragma unroll
        for (int c = 0; c < 64; ++c) {
            const float4 a = kb4[c * 64 + lane];
            const float vv = fmaf(a.x, m2qx, fmaf(a.y, m2qy, a.z));
            const bool acc = vv <= thr;
            const u64 mk = __ballot(acc);
            if (mk) {
                const int pos = cnt + mbcnt64(mk);
                if (acc && pos < CMAX)
                    cand[wv][pos] = (((u64)fkey(vv)) << 32) | (u32)(c * 64 + lane);
                cnt += __popcll(mk);
            }
        }
    } else {
#pragma unroll
        for (int c = 0; c < 32; ++c) {
            const float4 kk = kp4[c * 64 + lane];
            const float dx0 = qx - kk.x, dy0 = qy - kk.y;
            const float dx1 = qx - kk.z, dy1 = qy - kk.w;
            const float v0 = fmaf(dx0, dx0, dy0 * dy0);
            const float v1 = fmaf(dx1, dx1, dy1 * dy1);
            const bool a0 = v0 <= thr;
            u64 mk = __ballot(a0);
            if (mk) {
                const int pos = cnt + mbcnt64(mk);
                if (a0 && pos < CMAX)
                    cand[wv][pos] = (((u64)fkey(v0)) << 32) | (u32)(2 * (c * 64 + lane));
                cnt += __popcll(mk);
            }
            const bool a1 = v1 <= thr;
            mk = __ballot(a1);
            if (mk) {
                const int pos = cnt + mbcnt64(mk);
                if (a1 && pos < CMAX)
                    cand[wv][pos] = (((u64)fkey(v1)) << 32) | (u32)(2 * (c * 64 + lane) + 1);
                cnt += __popcll(mk);
            }
        }
    }

    /* ---- overflow fallback (~never): exact rank-16 via bit binary search ---- */
    if (cnt > CMAX) {
        u32 lo = 0, hi = ~0u;
        while (lo < hi) {
            const u32 mid = lo + ((hi - lo) >> 1);
            int cc = 0;
#pragma unroll 1
            for (int c = 0; c < 64; ++c) {
                float vv;
                if (MODE == 0) {
                    const float4 a = kb4[c * 64 + lane];
                    vv = fmaf(a.x, m2qx, fmaf(a.y, m2qy, a.z));
                } else {
                    const float2 kc2 = kp[c * 64 + lane];
                    const float dx = qx - kc2.x, dy = qy - kc2.y;
                    vv = fmaf(dx, dx, dy * dy);
                }
                cc += (fkey(vv) <= mid) ? 1 : 0;
            }
#pragma unroll
            for (int off = 32; off; off >>= 1) cc += __shfl_xor(cc, off);
            if (cc >= KSEL) hi = mid; else lo = mid + 1;
        }
        cnt = 0;
#pragma unroll 1
        for (int c = 0; c < 64; ++c) {
            float vv;
            if (MODE == 0) {
                const float4 a = kb4[c * 64 + lane];
                vv = fmaf(a.x, m2qx, fmaf(a.y, m2qy, a.z));
            } else {
                const float2 kc2 = kp[c * 64 + lane];
                const float dx = qx - kc2.x, dy = qy - kc2.y;
                vv = fmaf(dx, dx, dy * dy);
            }
            const u32 tb = fkey(vv);
            const bool acc = tb <= lo;
            const u64 mk = __ballot(acc);
            if (mk) {
                const int pos = cnt + mbcnt64(mk);
                if (acc && pos < CMAX)
                    cand[wv][pos] = (((u64)tb) << 32) | (u32)(c * 64 + lane);
                cnt += __popcll(mk);
            }
        }
        if (cnt > CMAX) cnt = CMAX;
    }

    /* ---- exact top-16 set by (metric, idx): lanes 0..15 win ---- */
    u64 myv = (lane < cnt) ? cand[wv][lane] : PADU;
    myv = top16of64(myv, lane);
    const u32 myidx = (u32)myv;

    /* ---- affine scores + width-16 softmax (order-invariant) ---- */
    const float A  = fmaf(qx, w9[0], fmaf(qy, w9[1], w9[2]));
    const float Bb = fmaf(qx, w9[3], fmaf(qy, w9[4], w9[5]));
    const float Cc = fmaf(qx, w9[6], fmaf(qy, w9[7], w9[8]));

    const int sel = (lane < KSEL) ? (int)myidx : 0;
    const float2 kc = kp[sel];
    const float score = fmaf(A, kc.x, fmaf(Bb, kc.y, Cc));
    float mx = score;
#pragma unroll
    for (int off = 8; off; off >>= 1) mx = fmaxf(mx, __shfl_xor(mx, off));
    const float e = __expf(score - mx);
    float sum = e;
#pragma unroll
    for (int off = 8; off; off >>= 1) sum += __shfl_xor(sum, off);
    const float w = e / sum;                          /* valid in lanes 0..15 */

    /* ---- V gather: readlane-broadcast scalar base, lane = channel ---- */
    const float* vb = vg + (size_t)b * NKEY * CV;
    float acc = 0.f;
#pragma unroll
    for (int s = 0; s < KSEL; ++s) {
        const u32 id   = (u32)__builtin_amdgcn_readlane((int)myidx, s);
        const float ws = __uint_as_float(
            (u32)__builtin_amdgcn_readlane((int)__float_as_uint(w), s));
        acc = fmaf(ws, vb[(size_t)id * CV + lane], acc);
    }
    outg[((size_t)b * NQ + qi) * CV + lane] = acc;
}

extern "C" void kernel_launch(void* const* d_in, const int* in_sizes, int n_in,
                              void* d_out, int out_size, void* d_ws, size_t ws_size,
                              hipStream_t stream) {
    const float* q  = (const float*)d_in[0];
    const float* k  = (const float*)d_in[1];
    const float* v  = (const float*)d_in[2];
    const float* qw = (const float*)d_in[3];
    const float* qb = (const float*)d_in[4];
    const float* kw = (const float*)d_in[5];
    const float* kb = (const float*)d_in[6];
    /* d_in[7] = top_k (always 16; compile-time) */
    float* out = (float*)d_out;

    float*  w9  = (float*)d_ws;
    float4* kq4 = (float4*)((char*)d_ws + 256);
    const size_t need = 256 + (size_t)NB * NKEY * sizeof(float4);
    const int mode0 = (ws_size >= need) ? 1 : 0;

    hipLaunchKernelGGL(setup_kernel, dim3(mode0 ? (NB * NKEY / 256) : 1), dim3(256),
                       0, stream, k, qw, qb, kw, kb, w9, kq4, mode0);
    if (mode0)
        hipLaunchKernelGGL((bev_main<0>), dim3(NB * NQ / NWAVE), dim3(BLK),
                           0, stream, q, k, v, w9, kq4, out);
    else
        hipLaunchKernelGGL((bev_main<1>), dim3(NB * NQ / NWAVE), dim3(BLK),
                           0, stream, q, k, v, w9, kq4, out);
}

// Round 7
// 74.856 us; speedup vs baseline: 2.4939x; 2.4939x over previous
//
#include <hip/hip_runtime.h>
#include <stdint.h>

typedef uint64_t u64;
typedef uint32_t u32;

#define NB    8
#define NQ    4096
#define NKEY  4096
#define CV    64
#define KSEL  16
#define G     8              /* queries per wave */
#define NWAVE 4              /* waves per block */
#define BLK   (NWAVE * 64)   /* 256 threads */
#define CMAX  64             /* candidate slots per query */
#define PADU  (~(u64)0)

__device__ __forceinline__ u64 shflxor_u64(u64 v, int m) {
    const u32 lo = __shfl_xor((int)(u32)v, m);
    const u32 hi = __shfl_xor((int)(u32)(v >> 32), m);
    return (((u64)hi) << 32) | lo;
}
__device__ __forceinline__ int mbcnt64(u64 m) {
    return (int)__builtin_amdgcn_mbcnt_hi((u32)(m >> 32),
               __builtin_amdgcn_mbcnt_lo((u32)m, 0));
}
/* monotone float -> u32 key (metric can be negative: d2 - q2) */
__device__ __forceinline__ u32 fkey(float f) {
    const u32 b = __float_as_uint(f);
    return b ^ (0x80000000u | (u32)((int32_t)b >> 31));
}

/* full 64-lane bitonic sort, ascending (threshold order-statistic) */
__device__ __forceinline__ float lanesort64_f32(float v, int lane) {
#pragma unroll
    for (int k = 2; k <= 64; k <<= 1) {
#pragma unroll
        for (int j = k >> 1; j > 0; j >>= 1) {
            const float p = __shfl_xor(v, j);
            const bool up    = ((lane & k) == 0);
            const bool lower = ((lane & j) == 0);
            v = (lower == up) ? fminf(v, p) : fmaxf(v, p);
        }
    }
    return v;
}

/* EXACT smallest-16 SET of 64 lane values -> lanes 0..15.
   sort16/group (alt dirs) -> xor16 half-clean -> merge16 asc/desc -> xor32. */
__device__ __forceinline__ u64 top16of64(u64 v, int lane) {
#pragma unroll
    for (int k = 2; k <= 16; k <<= 1) {
#pragma unroll
        for (int j = k >> 1; j > 0; j >>= 1) {
            const u64 p = shflxor_u64(v, j);
            const bool up    = ((lane & k) == 0);
            const bool lower = ((lane & j) == 0);
            const u64 mn = v < p ? v : p, mx = v < p ? p : v;
            v = (lower == up) ? mn : mx;
        }
    }
    {   const u64 p = shflxor_u64(v, 16);
        const u64 mn = v < p ? v : p, mx = v < p ? p : v;
        v = ((lane & 16) == 0) ? mn : mx; }
#pragma unroll
    for (int j = 8; j > 0; j >>= 1) {
        const u64 p = shflxor_u64(v, j);
        const bool lower = ((lane & j) == 0);
        const bool dasc  = ((lane & 32) == 0);
        const u64 mn = v < p ? v : p, mx = v < p ? p : v;
        v = (lower == dasc) ? mn : mx;
    }
    {   const u64 p = shflxor_u64(v, 32);
        const u64 mn = v < p ? v : p, mx = v < p ? p : v;
        v = ((lane & 32) == 0) ? mn : mx; }
    return v;
}

/* setup: 9 query-independent affine sums over H=64 -> d_ws */
__global__ void setup_kernel(const float* __restrict__ qw, const float* __restrict__ qb,
                             const float* __restrict__ kw, const float* __restrict__ kb,
                             float* __restrict__ w9)
{
    const int h = threadIdx.x & 63;
    const float2 a = ((const float2*)qw)[h];
    const float2 c = ((const float2*)kw)[h];
    const float qbh = qb[h], kbh = kb[h];
    float s[9] = { a.x * c.x, a.y * c.x, qbh * c.x,
                   a.x * c.y, a.y * c.y, qbh * c.y,
                   a.x * kbh, a.y * kbh, qbh * kbh };
#pragma unroll
    for (int i = 0; i < 9; ++i)
#pragma unroll
        for (int off = 32; off; off >>= 1) s[i] += __shfl_xor(s[i], off);
    if (h == 0) {
#pragma unroll
        for (int i = 0; i < 9; ++i) w9[i] = s[i];
    }
}

extern "C" __global__ __launch_bounds__(BLK, 4) void bev_main(
    const float* __restrict__ qg, const float* __restrict__ kg,
    const float* __restrict__ vg, const float* __restrict__ w9,
    float* __restrict__ outg)
{
    __shared__ u64 cand[NWAVE][G][CMAX];      /* 16 KB; per-wave private */

    const int tid  = threadIdx.x;
    const int wv   = tid >> 6;
    const int lane = tid & 63;
    const int wvu  = __builtin_amdgcn_readfirstlane(wv);
    const int b    = blockIdx.x >> 7;                  /* 128 blocks per batch */
    const int qbase = ((int)(blockIdx.x & 127) * NWAVE + wvu) * G;

    const float2* kp  = (const float2*)(kg + (size_t)b * NKEY * 2);
    const float4* kp4 = (const float4*)kp;             /* 2 keys / 16 B */
    const float2* qp  = (const float2*)qg + (size_t)b * NQ + qbase;

    /* wave-uniform query coords (scalar-loadable: index chain is scalar) */
    float qxx[G], qyy[G], m2x[G], m2y[G];
#pragma unroll
    for (int q = 0; q < G; ++q) {
        const float2 qc = qp[q];
        qxx[q] = qc.x; qyy[q] = qc.y;
        m2x[q] = -2.f * qc.x; m2y[q] = -2.f * qc.y;
    }

    /* ---- pass 1: per-lane metric-min for each of G queries (shared key loads) */
    float mn[G];
#pragma unroll
    for (int q = 0; q < G; ++q) mn[q] = __builtin_inff();
#pragma unroll 8
    for (int c = 0; c < 32; ++c) {
        const float4 kk = kp4[c * 64 + lane];
        const float k2a = fmaf(kk.x, kk.x, kk.y * kk.y);
        const float k2b = fmaf(kk.z, kk.z, kk.w * kk.w);
#pragma unroll
        for (int q = 0; q < G; ++q) {
            const float va = fmaf(kk.x, m2x[q], fmaf(kk.y, m2y[q], k2a));
            const float vb = fmaf(kk.z, m2x[q], fmaf(kk.w, m2y[q], k2b));
            mn[q] = fminf(mn[q], fminf(va, vb));
        }
    }

    /* ---- thresholds: 16th-smallest of 64 lane-mins (>=16 keys <= thr) ---- */
    float thr[G];
#pragma unroll
    for (int q = 0; q < G; ++q)
        thr[q] = __shfl(lanesort64_f32(mn[q], lane), 15);

    /* ---- pass 2: recompute metrics, ballot-append all <= thr per query ---- */
    int cnt[G];
#pragma unroll
    for (int q = 0; q < G; ++q) cnt[q] = 0;
#pragma unroll 4
    for (int c = 0; c < 32; ++c) {
        const float4 kk = kp4[c * 64 + lane];
        const float k2a = fmaf(kk.x, kk.x, kk.y * kk.y);
        const float k2b = fmaf(kk.z, kk.z, kk.w * kk.w);
        const u32 ia = (u32)(2 * (c * 64 + lane));
#pragma unroll
        for (int q = 0; q < G; ++q) {
            const float va = fmaf(kk.x, m2x[q], fmaf(kk.y, m2y[q], k2a));
            const float vb = fmaf(kk.z, m2x[q], fmaf(kk.w, m2y[q], k2b));
            const bool aa = va <= thr[q];
            const bool ab = vb <= thr[q];
            const u64 mka = __ballot(aa);
            const u64 mkb = __ballot(ab);
            if (mka | mkb) {                           /* uniform, ~1% taken */
                const int posa = cnt[q] + mbcnt64(mka);
                cnt[q] += (int)__popcll(mka);
                const int posb = cnt[q] + mbcnt64(mkb);
                cnt[q] += (int)__popcll(mkb);
                if (aa && posa < CMAX)
                    cand[wv][q][posa] = (((u64)fkey(va)) << 32) | ia;
                if (ab && posb < CMAX)
                    cand[wv][q][posb] = (((u64)fkey(vb)) << 32) | (ia + 1);
            }
        }
    }

    /* ---- overflow fallback (~never): exact rank-16 via bit binary search ---- */
#pragma unroll
    for (int q = 0; q < G; ++q) {
        if (cnt[q] > CMAX) {
            u32 lo = 0, hi = ~0u;
            while (lo < hi) {
                const u32 mid = lo + ((hi - lo) >> 1);
                int cc = 0;
#pragma unroll 1
                for (int c = 0; c < 32; ++c) {
                    const float4 kk = kp4[c * 64 + lane];
                    const float k2a = fmaf(kk.x, kk.x, kk.y * kk.y);
                    const float k2b = fmaf(kk.z, kk.z, kk.w * kk.w);
                    const float va = fmaf(kk.x, m2x[q], fmaf(kk.y, m2y[q], k2a));
                    const float vb = fmaf(kk.z, m2x[q], fmaf(kk.w, m2y[q], k2b));
                    cc += (fkey(va) <= mid) ? 1 : 0;
                    cc += (fkey(vb) <= mid) ? 1 : 0;
                }
#pragma unroll
                for (int off = 32; off; off >>= 1) cc += __shfl_xor(cc, off);
                if (cc >= KSEL) hi = mid; else lo = mid + 1;
            }
            int cc = 0;
#pragma unroll 1
            for (int c = 0; c < 32; ++c) {
                const float4 kk = kp4[c * 64 + lane];
                const float k2a = fmaf(kk.x, kk.x, kk.y * kk.y);
                const float k2b = fmaf(kk.z, kk.z, kk.w * kk.w);
                const float va = fmaf(kk.x, m2x[q], fmaf(kk.y, m2y[q], k2a));
                const float vb = fmaf(kk.z, m2x[q], fmaf(kk.w, m2y[q], k2b));
                const u32 ta = fkey(va), tb = fkey(vb);
                const bool aa = ta <= lo, ab = tb <= lo;
                const u64 mka = __ballot(aa);
                const u64 mkb = __ballot(ab);
                const int posa = cc + mbcnt64(mka);
                cc += (int)__popcll(mka);
                const int posb = cc + mbcnt64(mkb);
                cc += (int)__popcll(mkb);
                const u32 ia = (u32)(2 * (c * 64 + lane));
                if (aa && posa < CMAX) cand[wv][q][posa] = (((u64)ta) << 32) | ia;
                if (ab && posb < CMAX) cand[wv][q][posb] = (((u64)tb) << 32) | (ia + 1);
            }
            cnt[q] = cc < CMAX ? cc : CMAX;
        }
    }

    /* ---- per query: exact top-16, affine scores, softmax, V gather ---- */
    const float s1 = w9[0], s2 = w9[1], s3 = w9[2];
    const float s4 = w9[3], s5 = w9[4], s6 = w9[5];
    const float s7 = w9[6], s8 = w9[7], s9 = w9[8];
    const float* vb = vg + (size_t)b * NKEY * CV;

#pragma unroll 1
    for (int q = 0; q < G; ++q) {
        u64 myv = (lane < cnt[q]) ? cand[wv][q][lane] : PADU;
        myv = top16of64(myv, lane);
        const u32 myidx = (u32)myv;

        const float A  = fmaf(qxx[q], s1, fmaf(qyy[q], s2, s3));
        const float Bb = fmaf(qxx[q], s4, fmaf(qyy[q], s5, s6));
        const float Cc = fmaf(qxx[q], s7, fmaf(qyy[q], s8, s9));

        const int sel = (lane < KSEL) ? (int)myidx : 0;
        const float2 kc = kp[sel];
        const float score = fmaf(A, kc.x, fmaf(Bb, kc.y, Cc));
        float mx = score;
#pragma unroll
        for (int off = 8; off; off >>= 1) mx = fmaxf(mx, __shfl_xor(mx, off));
        const float e = __expf(score - mx);
        float sum = e;
#pragma unroll
        for (int off = 8; off; off >>= 1) sum += __shfl_xor(sum, off);
        const float w = e / sum;                       /* valid in lanes 0..15 */

        float acc = 0.f;
#pragma unroll
        for (int s = 0; s < KSEL; ++s) {
            const u32 id   = (u32)__builtin_amdgcn_readlane((int)myidx, s);
            const float ws = __uint_as_float(
                (u32)__builtin_amdgcn_readlane((int)__float_as_uint(w), s));
            acc = fmaf(ws, vb[(size_t)id * CV + lane], acc);
        }
        outg[((size_t)b * NQ + qbase + q) * CV + lane] = acc;
    }
}

extern "C" void kernel_launch(void* const* d_in, const int* in_sizes, int n_in,
                              void* d_out, int out_size, void* d_ws, size_t ws_size,
                              hipStream_t stream) {
    const float* q  = (const float*)d_in[0];
    const float* k  = (const float*)d_in[1];
    const float* v  = (const float*)d_in[2];
    const float* qw = (const float*)d_in[3];
    const float* qb = (const float*)d_in[4];
    const float* kw = (const float*)d_in[5];
    const float* kb = (const float*)d_in[6];
    /* d_in[7] = top_k (always 16; compile-time) */
    float* out = (float*)d_out;
    float* w9  = (float*)d_ws;

    hipLaunchKernelGGL(setup_kernel, dim3(1), dim3(64), 0, stream,
                       qw, qb, kw, kb, w9);
    hipLaunchKernelGGL(bev_main, dim3(NB * NQ / (G * NWAVE)), dim3(BLK),
                       0, stream, q, k, v, w9, out);
}